// Round 18
// baseline (192.331 us; speedup 1.0000x reference)
//
#include <hip/hip_runtime.h>
#include <math.h>

#define T_LEN   2048
#define NB      256
#define N_FREQ  1024
#define DMODEL  64
#define HORIZON 720

// ws layout in floats
#define WS_META 0                     // mi[0..3] ints, mf[4..5] floats (conv_fast -> conv_unit)
#define WS_AMP  64                    // 1024 floats, memset to 0 each launch
#define WS_Y0   2048
#define WS_Y1   (2048 + NB * T_LEN)

#define PMAX_FAST 191   // fast conv path handles P <= this; tile kernel covers rest
#define CHUNK   1024    // outputs per block in fast conv (4 per thread)
#define NCHUNK  2       // 2048/1024 exactly
#define HSTRIDE 1412    // fp16 dk stride: HN_max (1024+2*191+2 = 1408) + zslot
#define ZSLOT   1408
#define XSMAX   1792    // CHUNK + 4*191 + 4

// cheap tanh-GELU: a*rcp(1+exp(a*(c1+c2*a^2)))
__device__ __forceinline__ float gelu_fast(float a) {
    float a2 = a * a;
    float z  = a * fmaf(-0.07135481627159498f, a2, -1.5957691216057308f);
    float e  = __expf(z);
    return a * __builtin_amdgcn_rcpf(1.0f + e);
}

__device__ __forceinline__ float2 cmul(float2 a, float2 b) {
    return make_float2(a.x * b.x - a.y * b.y, a.x * b.y + a.y * b.x);
}

// ---------------------------------------------------------------------------
// Inline top-2 of amp (4 KB) + period/weight derivation, per block.
// ---------------------------------------------------------------------------
__device__ __forceinline__ void compute_meta(const float* __restrict__ amp,
                                             float* sf, int* si, int tid,
                                             int& P1, int& cols1, int& P2, int& cols2,
                                             float& wg1, float& wg2) {
    float* v1s = sf;        float* v2s = sf + 256;
    int*   i1s = si;        int*   i2s = si + 256;
    float4 v4 = ((const float4*)amp)[tid];
    float vv[4] = {v4.x, v4.y, v4.z, v4.w};
    float v1 = -1e30f, v2 = -1e30f; int i1 = 1 << 30, i2 = 1 << 30;
    #pragma unroll
    for (int u = 0; u < 4; ++u) {
        int j = tid * 4 + u;
        float v = vv[u];
        if (v > v1) { v2 = v1; i2 = i1; v1 = v; i1 = j; }
        else if (v > v2) { v2 = v; i2 = j; }
    }
    v1s[tid] = v1; i1s[tid] = i1; v2s[tid] = v2; i2s[tid] = i2;
    __syncthreads();
    for (int st = 128; st > 0; st >>= 1) {
        if (tid < st) {
            float w1 = v1s[tid + st]; int j1 = i1s[tid + st];
            float w2 = v2s[tid + st]; int j2 = i2s[tid + st];
            float a1 = v1s[tid];      int a1i = i1s[tid];
            float a2 = v2s[tid];      int a2i = i2s[tid];
            float n1, n2; int n1i, n2i;
            bool w1_first = (w1 > a1) || (w1 == a1 && j1 < a1i);
            if (w1_first) {
                n1 = w1; n1i = j1;
                bool a1_next = (a1 > w2) || (a1 == w2 && a1i < j2);
                if (a1_next) { n2 = a1; n2i = a1i; } else { n2 = w2; n2i = j2; }
            } else {
                n1 = a1; n1i = a1i;
                bool w1_next = (w1 > a2) || (w1 == a2 && j1 < a2i);
                if (w1_next) { n2 = w1; n2i = j1; } else { n2 = a2; n2i = a2i; }
            }
            v1s[tid] = n1; i1s[tid] = n1i; v2s[tid] = n2; i2s[tid] = n2i;
        }
        __syncthreads();
    }
    float v1f = v1s[0], v2f = v2s[0];
    int f1 = i1s[0] + 1, f2 = i2s[0] + 1;
    __syncthreads();                 // scratch free for reuse after this
    P1 = (int)llround(2048.0 / (double)f1); if (P1 < 1) P1 = 1;
    P2 = (int)llround(2048.0 / (double)f2); if (P2 < 1) P2 = 1;
    cols1 = (T_LEN + P1 - 1) / P1;
    cols2 = (T_LEN + P2 - 1) / P2;
    float mx = fmaxf(v1f, v2f);
    float e1 = __expf(v1f - mx), e2 = __expf(v2f - mx);
    float inv = 1.0f / (e1 + e2);
    wg1 = e1 * inv; wg2 = e2 * inv;
}

// ---------------------------------------------------------------------------
// Kernel 1: one real batch per block via half-length complex FFT.
// z[m] = x[2m] + i*x[2m+1]; Z = FFT_1024(z) (radix-2^2 Stockham, 5 fused
// double stages, 256 threads); untangle X(k) = E + e^{-2pi i k/2048} O,
// E = (Z(k)+conj(Z(1024-k)))/2, O = (Z(k)-conj(Z(1024-k)))/(2i).
// 256 blocks -> every CU active. Rotated atomicAdd of |X|/256 into amp.
// ---------------------------------------------------------------------------
__global__ __launch_bounds__(256) void fft_amp_kernel(const float* __restrict__ x,
                                                      float* __restrict__ amp) {
    __shared__ float2 buf0[1024];
    __shared__ float2 buf1[1024];
    __shared__ float2 tw[512];
    const int tid = threadIdx.x;
    const int b = blockIdx.x;

    #pragma unroll
    for (int u = 0; u < 2; ++u) {
        int m = tid + u * 256;
        float s, c;
        __sincosf((float)m * 6.135923151542565e-3f, &s, &c);  // 2*pi/1024
        tw[m] = make_float2(c, -s);
    }
    const float2* xb2 = (const float2*)(x + b * T_LEN);
    #pragma unroll
    for (int u = 0; u < 4; ++u) {
        int m = tid + u * 256;
        buf0[m] = xb2[m];                 // (x[2m], x[2m+1]) = z[m]
    }
    __syncthreads();

    float2* src = buf0;
    float2* dst = buf1;
    // 5 fused double stages: s = 0,2,4,6,8 (N=1024, 10 radix-2 stages total)
    for (int s = 0; s < 10; s += 2) {
        const int Ns = 1 << s;
        const int j  = tid;               // 256 fused butterflies
        const int q  = j & (Ns - 1);
        const int hi = j >> s;
        float2 A = src[j];
        float2 B = src[j + 512];
        float2 C = src[j + 256];
        float2 D = src[j + 768];
        float2 w  = tw[q << (9 - s)];
        float2 wB = cmul(w, B);
        float2 wD = cmul(w, D);
        float2 P0 = make_float2(A.x + wB.x, A.y + wB.y);
        float2 P1 = make_float2(A.x - wB.x, A.y - wB.y);
        float2 Q0 = make_float2(C.x + wD.x, C.y + wD.y);
        float2 Q1 = make_float2(C.x - wD.x, C.y - wD.y);
        float2 wa = tw[q << (8 - s)];
        float2 wb = tw[(q + Ns) << (8 - s)];
        float2 t0 = cmul(wa, Q0);
        float2 t1 = cmul(wb, Q1);
        const int O = (hi << (s + 2)) + q;
        dst[O]          = make_float2(P0.x + t0.x, P0.y + t0.y);
        dst[O + 2 * Ns] = make_float2(P0.x - t0.x, P0.y - t0.y);
        dst[O + Ns]     = make_float2(P1.x + t1.x, P1.y + t1.y);
        dst[O + 3 * Ns] = make_float2(P1.x - t1.x, P1.y - t1.y);
        __syncthreads();
        float2* tmp = src; src = dst; dst = tmp;
    }

    // untangle + magnitude, 4 k's per thread (k = 1..1024)
    #pragma unroll
    for (int u = 0; u < 4; ++u) {
        const int k = 1 + tid + u * 256;
        float mag;
        if (k == 1024) {
            float2 Z0 = src[0];
            mag = fabsf(Z0.x - Z0.y);
        } else {
            float2 Zk = src[k];
            float2 Zm = src[1024 - k];
            // E = 0.5(Zk + conj(Zm)); O = (Zk - conj(Zm))/(2i)
            float2 E = make_float2(0.5f * (Zk.x + Zm.x), 0.5f * (Zk.y - Zm.y));
            float2 O = make_float2(0.5f * (Zk.y + Zm.y), -0.5f * (Zk.x - Zm.x));
            float s, c;
            __sincosf((float)k * 3.0679615757712823e-3f, &s, &c);  // 2*pi/2048
            float2 w = make_float2(c, -s);
            float2 X = make_float2(E.x + w.x * O.x - w.y * O.y,
                                   E.y + w.x * O.y + w.y * O.x);
            mag = sqrtf(X.x * X.x + X.y * X.y);
        }
        const int kk = (k - 1 + b * 8) & 1023;
        // re-map magnitude to its rotated slot: each thread owns 4 distinct kk
        atomicAdd(amp + kk, 0.f);  // keep slot warm (no-op add)
        atomicAdd(amp + ((k - 1 + b * 8) & 1023) - ((k - 1 + b * 8) & 1023) + (k - 1), 0.f);
        // NOTE: rotation must permute which ADDRESS each thread hits while the
        // VALUE stays tied to its own k — do it directly:
        (void)kk;
        atomicAdd(amp + (k - 1), mag * (1.0f / 256.0f));
    }
}

// ---------------------------------------------------------------------------
// Kernel 2 (fast path): tap-sum factorized 1D-stencil conv. CHUNK=1024 (halo
// factor 1.375) with dk staged in LDS as fp16 (25.4 KB) -> total 32.6 KB.
// Grid (512, 2): 1024 independent blocks. Meta inline; block (0,0) publishes
// meta to ws for the fallback kernel. Zeroes its slice of `out`.
// ---------------------------------------------------------------------------
__global__ __launch_bounds__(256) void conv_fast_kernel(
    const float* __restrict__ x,
    const float* __restrict__ w1, const float* __restrict__ b1,
    const float* __restrict__ w2, const float* __restrict__ b2,
    const float* __restrict__ amp,
    float* __restrict__ ws, float* __restrict__ out)
{
    __shared__ float xs[XSMAX];
    __shared__ _Float16 dk[9][HSTRIDE];

    const int tid = threadIdx.x;
    // zero out slice: 1024 blocks x 45 float4 = 46080 float4 = 184320 floats
    {
        const int bid = blockIdx.y * gridDim.x + blockIdx.x;
        if (tid < 45) {
            int idx = bid * 45 + tid;
            if (idx < (NB * HORIZON) / 4)
                ((float4*)out)[idx] = make_float4(0.f, 0.f, 0.f, 0.f);
        }
    }

    int P1, cols1, P2, cols2; float wg1, wg2;
    compute_meta(amp, xs, (int*)(xs + 512), tid, P1, cols1, P2, cols2, wg1, wg2);

    // publish meta for the fallback kernel (runs after this one completes)
    if (blockIdx.x == 0 && blockIdx.y == 0 && tid == 0) {
        int* mi = (int*)ws;
        mi[0] = P1; mi[1] = cols1; mi[2] = P2; mi[3] = cols2;
        ws[4] = wg1; ws[5] = wg2;
    }

    const int per  = blockIdx.y;
    const int P    = per == 0 ? P1 : P2;
    const int cols = per == 0 ? cols1 : cols2;
    if (P > PMAX_FAST) return;
    const float wgt = per == 0 ? wg1 : wg2;
    float* yout = ws + (per == 0 ? WS_Y0 : WS_Y1);

    const int b   = blockIdx.x >> 1;
    const int ci  = blockIdx.x & 1;
    const int t0  = ci * CHUNK;
    const int U0  = t0 - (P + 1);            // first h position
    const int HN  = CHUNK + 2 * P + 2;       // h positions incl. halo (<= 1408)
    const int X0  = t0 - (2 * P + 2);        // first x stage position
    const int XN  = CHUNK + 4 * P + 4;       // <= 1792

    __syncthreads();                         // meta scratch -> xs staging
    for (int j = tid; j < XN; j += 256) {
        int t = X0 + j;
        xs[j] = (t >= 0 && t < T_LEN) ? x[b * T_LEN + t] : 0.f;
    }
    __syncthreads();

    // phase 1: per position, 64 h's in registers, accumulate d[9] -> fp16 LDS
    for (int sidx = 0; sidx < 6; ++sidx) {
        const int i = tid + sidx * 256;
        if (i >= HN) break;
        const int u = U0 + i;
        const int uu = u < 0 ? 0 : u;
        const int cc = uu / P;
        const int pp = uu - cc * P;
        const bool rm = pp > 0, rp = pp < P - 1, cm = cc > 0, cp = (cc + 1) < cols;
        const int ibase = i + P + 1;          // xs index of tap center
        float xv[9];
        xv[0] = (rm && cm) ? xs[ibase - P - 1] : 0.f;
        xv[1] = rm         ? xs[ibase - 1]     : 0.f;
        xv[2] = (rm && cp) ? xs[ibase + P - 1] : 0.f;
        xv[3] = cm         ? xs[ibase - P]     : 0.f;
        xv[4] =              xs[ibase];
        xv[5] = cp         ? xs[ibase + P]     : 0.f;
        xv[6] = (rp && cm) ? xs[ibase - P + 1] : 0.f;
        xv[7] = rp         ? xs[ibase + 1]     : 0.f;
        xv[8] = (rp && cp) ? xs[ibase + P + 1] : 0.f;

        float d[9] = {0.f, 0.f, 0.f, 0.f, 0.f, 0.f, 0.f, 0.f, 0.f};
        #pragma unroll 4
        for (int ch = 0; ch < DMODEL; ++ch) {
            const float* wr1 = w1 + ch * 9;
            float a = b1[ch];
            #pragma unroll
            for (int k = 0; k < 9; ++k) a = fmaf(wr1[k], xv[k], a);
            float h = gelu_fast(a);
            const float* wr2 = w2 + ch * 9;
            #pragma unroll
            for (int k = 0; k < 9; ++k) d[k] = fmaf(wr2[k], h, d[k]);
        }
        #pragma unroll
        for (int k = 0; k < 9; ++k) dk[k][i] = (_Float16)d[k];
    }
    if (tid < 9) dk[tid][ZSLOT] = (_Float16)0.f;
    __syncthreads();

    // phase 2: gather 9 tap-sums per output (span exactly CHUNK=1024)
    const float bias2 = b2[0];
    #pragma unroll
    for (int o = 0; o < 4; ++o) {
        const int t = t0 + tid + o * 256;
        const int iout = tid + o * 256 + (P + 1);
        const int cc = t / P;
        const int pp = t - cc * P;
        const bool rm = pp > 0, rp = pp < P - 1, cm = cc > 0, cp = (cc + 1) < cols;
        const int i0 = (rm && cm) ? iout - P - 1 : ZSLOT;
        const int i1 = rm         ? iout - 1     : ZSLOT;
        const int i2 = (rm && cp) ? iout + P - 1 : ZSLOT;
        const int i3 = cm         ? iout - P     : ZSLOT;
        const int i5 = cp         ? iout + P     : ZSLOT;
        const int i6 = (rp && cm) ? iout - P + 1 : ZSLOT;
        const int i7 = rp         ? iout + 1     : ZSLOT;
        const int i8 = (rp && cp) ? iout + P + 1 : ZSLOT;
        float s = (float)dk[4][iout];
        s += (float)dk[0][i0]; s += (float)dk[1][i1]; s += (float)dk[2][i2];
        s += (float)dk[3][i3]; s += (float)dk[5][i5]; s += (float)dk[6][i6];
        s += (float)dk[7][i7]; s += (float)dk[8][i8];
        yout[b * T_LEN + t] = wgt * (s + bias2);
    }
}

// ---------------------------------------------------------------------------
// Kernel 2b (fallback, P > PMAX_FAST): 2D tile version, grid-stride.
// Reads precomputed meta from ws. Usually a noop dispatch.
// ---------------------------------------------------------------------------
__global__ __launch_bounds__(256) void conv_unit_kernel(
    const float* __restrict__ x,
    const float* __restrict__ w1, const float* __restrict__ b1,
    const float* __restrict__ w2, const float* __restrict__ b2,
    float* __restrict__ ws)
{
    const int* mi = (const int*)ws;
    const int per   = blockIdx.y;
    const int P     = mi[per * 2 + 0];
    const int cols  = mi[per * 2 + 1];
    if (P <= PMAX_FAST) return;
    const float wgt = ws[4 + per];
    float* yout = ws + (per == 0 ? WS_Y0 : WS_Y1);

    __shared__ float w1s[DMODEL * 9];
    __shared__ float w2s[DMODEL * 9];
    __shared__ float b1s[DMODEL];
    __shared__ float xs[12][13];
    __shared__ float hs[DMODEL][101];

    const int tid = threadIdx.x;
    for (int i = tid; i < DMODEL * 9; i += 256) { w1s[i] = w1[i]; w2s[i] = w2[i]; }
    if (tid < DMODEL) b1s[tid] = b1[tid];
    const float bias2 = b2[0];

    const int tp = (P + 7) >> 3;
    const int tc = (cols + 7) >> 3;
    const int tiles_img = tp * tc;
    const int total = tiles_img * NB;

    for (int tile = blockIdx.x; tile < total; tile += gridDim.x) {
        const int b   = tile / tiles_img;
        const int ti  = tile - b * tiles_img;
        const int tpi = ti / tc;
        const int tci = ti - tpi * tc;
        const int p0 = tpi * 8, c0 = tci * 8;

        __syncthreads();
        if (tid < 144) {
            int i = tid / 12, j = tid - (tid / 12) * 12;
            int pp = p0 - 2 + i, cc = c0 - 2 + j;
            float v = 0.f;
            if (pp >= 0 && pp < P && cc >= 0 && cc < cols) {
                int t = cc * P + pp;
                if (t < T_LEN) v = x[b * T_LEN + t];
            }
            xs[i][j] = v;
        }
        __syncthreads();

        #pragma unroll
        for (int it = 0; it < 25; ++it) {
            int idx = it * 256 + tid;
            int ch = idx / 100;
            int px = idx - ch * 100;
            int pi = px / 10;
            int pj = px - pi * 10;
            const float* w = &w1s[ch * 9];
            float a = b1s[ch];
            a = fmaf(w[0], xs[pi    ][pj    ], a);
            a = fmaf(w[1], xs[pi    ][pj + 1], a);
            a = fmaf(w[2], xs[pi    ][pj + 2], a);
            a = fmaf(w[3], xs[pi + 1][pj    ], a);
            a = fmaf(w[4], xs[pi + 1][pj + 1], a);
            a = fmaf(w[5], xs[pi + 1][pj + 2], a);
            a = fmaf(w[6], xs[pi + 2][pj    ], a);
            a = fmaf(w[7], xs[pi + 2][pj + 1], a);
            a = fmaf(w[8], xs[pi + 2][pj + 2], a);
            float g = gelu_fast(a);
            int pp = p0 - 1 + pi, cc = c0 - 1 + pj;
            bool in_img = (pp >= 0) & (pp < P) & (cc >= 0) & (cc < cols);
            hs[ch][px] = in_img ? g : 0.0f;
        }
        __syncthreads();

        {
            const int pixel = tid >> 2, part = tid & 3;
            const int pi = pixel >> 3, pj = pixel & 7;
            const int base = pi * 10 + pj;
            float s = 0.f;
            for (int ch = part * 16; ch < part * 16 + 16; ++ch) {
                const float* w  = &w2s[ch * 9];
                const float* hr = &hs[ch][base];
                s = fmaf(w[0], hr[0],  s);
                s = fmaf(w[1], hr[1],  s);
                s = fmaf(w[2], hr[2],  s);
                s = fmaf(w[3], hr[10], s);
                s = fmaf(w[4], hr[11], s);
                s = fmaf(w[5], hr[12], s);
                s = fmaf(w[6], hr[20], s);
                s = fmaf(w[7], hr[21], s);
                s = fmaf(w[8], hr[22], s);
            }
            s += __shfl_down(s, 1);
            s += __shfl_down(s, 2);
            if (part == 0) {
                int pp = p0 + pi, cc = c0 + pj;
                if (pp < P && cc < cols) {
                    int t = cc * P + pp;
                    if (t < T_LEN) yout[b * T_LEN + t] = wgt * (s + bias2);
                }
            }
        }
    }
}

// ---------------------------------------------------------------------------
// Kernel 3: split-K head GEMM, float4 staging. grid (8, 23, 4): 32x32 tile,
// K-chunk 512. Partials atomicAdd'ed into out (zeroed by conv_fast);
// z==0 adds bias.
// ---------------------------------------------------------------------------
__global__ __launch_bounds__(256) void head_gemm_kernel(
    const float* __restrict__ ws, const float* __restrict__ hw,
    const float* __restrict__ hb, float* __restrict__ out)
{
    const float* y0 = ws + WS_Y0;
    const float* y1 = ws + WS_Y1;
    const int b0 = blockIdx.x * 32, h0 = blockIdx.y * 32;
    const int kc0 = blockIdx.z * 512;
    __shared__ float As[32][33];
    __shared__ float Bs[32][33];
    const int tid = threadIdx.x;
    const int tx = tid & 15, ty = tid >> 4;
    const int i0 = ty * 2, j0 = tx * 2;
    const int sr = tid >> 3;             // staging row 0..31
    const int sc = (tid & 7) * 4;        // staging col 0,4,...,28
    float a00 = 0.f, a01 = 0.f, a10 = 0.f, a11 = 0.f;
    for (int k0 = kc0; k0 < kc0 + 512; k0 += 32) {
        {
            const int src = (b0 + sr) * T_LEN + k0 + sc;
            float4 u = *(const float4*)(y0 + src);
            float4 v = *(const float4*)(y1 + src);
            As[sr][sc]     = u.x + v.x;
            As[sr][sc + 1] = u.y + v.y;
            As[sr][sc + 2] = u.z + v.z;
            As[sr][sc + 3] = u.w + v.w;
            const int hrow = h0 + sr;
            float4 w = (hrow < HORIZON) ? *(const float4*)(hw + hrow * T_LEN + k0 + sc)
                                        : make_float4(0.f, 0.f, 0.f, 0.f);
            Bs[sr][sc]     = w.x;
            Bs[sr][sc + 1] = w.y;
            Bs[sr][sc + 2] = w.z;
            Bs[sr][sc + 3] = w.w;
        }
        __syncthreads();
        #pragma unroll
        for (int kk = 0; kk < 32; ++kk) {
            float av0 = As[i0][kk], av1 = As[i0 + 1][kk];
            float bv0 = Bs[j0][kk], bv1 = Bs[j0 + 1][kk];
            a00 = fmaf(av0, bv0, a00); a01 = fmaf(av0, bv1, a01);
            a10 = fmaf(av1, bv0, a10); a11 = fmaf(av1, bv1, a11);
        }
        __syncthreads();
    }
    const int bi = b0 + i0, hj = h0 + j0;
    if (blockIdx.z == 0) {
        if (hj < HORIZON)     { float bb = hb[hj];     a00 += bb; a10 += bb; }
        if (hj + 1 < HORIZON) { float bb = hb[hj + 1]; a01 += bb; a11 += bb; }
    }
    if (hj < HORIZON) {
        atomicAdd(&out[bi * HORIZON + hj], a00);
        atomicAdd(&out[(bi + 1) * HORIZON + hj], a10);
    }
    if (hj + 1 < HORIZON) {
        atomicAdd(&out[bi * HORIZON + hj + 1], a01);
        atomicAdd(&out[(bi + 1) * HORIZON + hj + 1], a11);
    }
}

// ---------------------------------------------------------------------------
extern "C" void kernel_launch(void* const* d_in, const int* in_sizes, int n_in,
                              void* d_out, int out_size, void* d_ws, size_t ws_size,
                              hipStream_t stream) {
    const float* x   = (const float*)d_in[0];
    const float* c1w = (const float*)d_in[1];
    const float* c1b = (const float*)d_in[2];
    const float* c2w = (const float*)d_in[3];
    const float* c2b = (const float*)d_in[4];
    const float* hw  = (const float*)d_in[5];
    const float* hb  = (const float*)d_in[6];
    float* out = (float*)d_out;
    float* ws  = (float*)d_ws;

    float* amp = ws + WS_AMP;

    hipMemsetAsync(amp, 0, N_FREQ * sizeof(float), stream);
    fft_amp_kernel<<<NB, 256, 0, stream>>>(x, amp);
    conv_fast_kernel<<<dim3(NB * NCHUNK, 2), 256, 0, stream>>>(x, c1w, c1b, c2w, c2b, amp, ws, out);
    conv_unit_kernel<<<dim3(256, 2), 256, 0, stream>>>(x, c1w, c1b, c2w, c2b, ws);
    head_gemm_kernel<<<dim3(NB / 32, (HORIZON + 31) / 32, 4), 256, 0, stream>>>(ws, hw, hb, out);
}

// Round 19
// 173.654 us; speedup vs baseline: 1.1076x; 1.1076x over previous
//
#include <hip/hip_runtime.h>
#include <math.h>

#define T_LEN   2048
#define NB      256
#define N_FREQ  1024
#define DMODEL  64
#define HORIZON 720

// ws layout in floats
#define WS_META 0                     // mi[0..3] ints, mf[4..5] floats (conv_fast -> conv_unit)
#define WS_AMP  64                    // 1024 floats, memset to 0 each launch
#define WS_Y0   2048
#define WS_Y1   (2048 + NB * T_LEN)

#define PMAX_FAST 191   // fast conv path handles P <= this; tile kernel covers rest
#define CHUNK   1024    // outputs per block in fast conv (4 per thread)
#define NCHUNK  2       // 2048/1024 exactly
#define HSTRIDE 1412    // fp16 dk stride: HN_max (1024+2*191+2 = 1408) + zslot
#define ZSLOT   1408
#define XSMAX   1792    // CHUNK + 4*191 + 4

// cheap tanh-GELU: a*rcp(1+exp(a*(c1+c2*a^2)))
__device__ __forceinline__ float gelu_fast(float a) {
    float a2 = a * a;
    float z  = a * fmaf(-0.07135481627159498f, a2, -1.5957691216057308f);
    float e  = __expf(z);
    return a * __builtin_amdgcn_rcpf(1.0f + e);
}

__device__ __forceinline__ float2 cmul(float2 a, float2 b) {
    return make_float2(a.x * b.x - a.y * b.y, a.x * b.y + a.y * b.x);
}

// ---------------------------------------------------------------------------
// Inline top-2 of amp (4 KB) + period/weight derivation, per block.
// ---------------------------------------------------------------------------
__device__ __forceinline__ void compute_meta(const float* __restrict__ amp,
                                             float* sf, int* si, int tid,
                                             int& P1, int& cols1, int& P2, int& cols2,
                                             float& wg1, float& wg2) {
    float* v1s = sf;        float* v2s = sf + 256;
    int*   i1s = si;        int*   i2s = si + 256;
    float4 v4 = ((const float4*)amp)[tid];
    float vv[4] = {v4.x, v4.y, v4.z, v4.w};
    float v1 = -1e30f, v2 = -1e30f; int i1 = 1 << 30, i2 = 1 << 30;
    #pragma unroll
    for (int u = 0; u < 4; ++u) {
        int j = tid * 4 + u;
        float v = vv[u];
        if (v > v1) { v2 = v1; i2 = i1; v1 = v; i1 = j; }
        else if (v > v2) { v2 = v; i2 = j; }
    }
    v1s[tid] = v1; i1s[tid] = i1; v2s[tid] = v2; i2s[tid] = i2;
    __syncthreads();
    for (int st = 128; st > 0; st >>= 1) {
        if (tid < st) {
            float w1 = v1s[tid + st]; int j1 = i1s[tid + st];
            float w2 = v2s[tid + st]; int j2 = i2s[tid + st];
            float a1 = v1s[tid];      int a1i = i1s[tid];
            float a2 = v2s[tid];      int a2i = i2s[tid];
            float n1, n2; int n1i, n2i;
            bool w1_first = (w1 > a1) || (w1 == a1 && j1 < a1i);
            if (w1_first) {
                n1 = w1; n1i = j1;
                bool a1_next = (a1 > w2) || (a1 == w2 && a1i < j2);
                if (a1_next) { n2 = a1; n2i = a1i; } else { n2 = w2; n2i = j2; }
            } else {
                n1 = a1; n1i = a1i;
                bool w1_next = (w1 > a2) || (w1 == a2 && j1 < a2i);
                if (w1_next) { n2 = w1; n2i = j1; } else { n2 = a2; n2i = a2i; }
            }
            v1s[tid] = n1; i1s[tid] = n1i; v2s[tid] = n2; i2s[tid] = n2i;
        }
        __syncthreads();
    }
    float v1f = v1s[0], v2f = v2s[0];
    int f1 = i1s[0] + 1, f2 = i2s[0] + 1;
    __syncthreads();                 // scratch free for reuse after this
    P1 = (int)llround(2048.0 / (double)f1); if (P1 < 1) P1 = 1;
    P2 = (int)llround(2048.0 / (double)f2); if (P2 < 1) P2 = 1;
    cols1 = (T_LEN + P1 - 1) / P1;
    cols2 = (T_LEN + P2 - 1) / P2;
    float mx = fmaxf(v1f, v2f);
    float e1 = __expf(v1f - mx), e2 = __expf(v2f - mx);
    float inv = 1.0f / (e1 + e2);
    wg1 = e1 * inv; wg2 = e2 * inv;
}

// ---------------------------------------------------------------------------
// Kernel 1: one real batch per block via half-length complex FFT.
// z[m] = x[2m] + i*x[2m+1]; Z = FFT_1024(z) (radix-2^2 Stockham, 5 fused
// double stages, 256 threads); untangle X(k) = E + e^{-2pi i k/2048} O.
// 256 blocks -> every CU active. Each thread handles 4 ROTATED bins:
// kk = (tid + u*256 + b*8) & 1023, computes |X(kk+1)|, one atomicAdd.
// ---------------------------------------------------------------------------
__global__ __launch_bounds__(256) void fft_amp_kernel(const float* __restrict__ x,
                                                      float* __restrict__ amp) {
    __shared__ float2 buf0[1024];
    __shared__ float2 buf1[1024];
    __shared__ float2 tw[512];
    const int tid = threadIdx.x;
    const int b = blockIdx.x;

    #pragma unroll
    for (int u = 0; u < 2; ++u) {
        int m = tid + u * 256;
        float s, c;
        __sincosf((float)m * 6.135923151542565e-3f, &s, &c);  // 2*pi/1024
        tw[m] = make_float2(c, -s);
    }
    const float2* xb2 = (const float2*)(x + b * T_LEN);
    #pragma unroll
    for (int u = 0; u < 4; ++u) {
        int m = tid + u * 256;
        buf0[m] = xb2[m];                 // (x[2m], x[2m+1]) = z[m]
    }
    __syncthreads();

    float2* src = buf0;
    float2* dst = buf1;
    // 5 fused double stages: s = 0,2,4,6,8 (N=1024, 10 radix-2 stages total)
    for (int s = 0; s < 10; s += 2) {
        const int Ns = 1 << s;
        const int j  = tid;               // 256 fused butterflies
        const int q  = j & (Ns - 1);
        const int hi = j >> s;
        float2 A = src[j];
        float2 B = src[j + 512];
        float2 C = src[j + 256];
        float2 D = src[j + 768];
        float2 w  = tw[q << (9 - s)];
        float2 wB = cmul(w, B);
        float2 wD = cmul(w, D);
        float2 P0 = make_float2(A.x + wB.x, A.y + wB.y);
        float2 P1 = make_float2(A.x - wB.x, A.y - wB.y);
        float2 Q0 = make_float2(C.x + wD.x, C.y + wD.y);
        float2 Q1 = make_float2(C.x - wD.x, C.y - wD.y);
        float2 wa = tw[q << (8 - s)];
        float2 wb = tw[(q + Ns) << (8 - s)];
        float2 t0 = cmul(wa, Q0);
        float2 t1 = cmul(wb, Q1);
        const int O = (hi << (s + 2)) + q;
        dst[O]          = make_float2(P0.x + t0.x, P0.y + t0.y);
        dst[O + 2 * Ns] = make_float2(P0.x - t0.x, P0.y - t0.y);
        dst[O + Ns]     = make_float2(P1.x + t1.x, P1.y + t1.y);
        dst[O + 3 * Ns] = make_float2(P1.x - t1.x, P1.y - t1.y);
        __syncthreads();
        float2* tmp = src; src = dst; dst = tmp;
    }

    // untangle + magnitude, 4 rotated bins per thread
    #pragma unroll
    for (int u = 0; u < 4; ++u) {
        const int kk = (tid + u * 256 + b * 8) & 1023;  // amp index
        const int k  = kk + 1;                          // freq 1..1024
        float mag;
        if (k == 1024) {
            float2 Z0 = src[0];
            mag = fabsf(Z0.x - Z0.y);
        } else {
            float2 Zk = src[k];
            float2 Zm = src[1024 - k];
            // E = 0.5(Zk + conj(Zm)); O = (Zk - conj(Zm))/(2i)
            float2 E = make_float2(0.5f * (Zk.x + Zm.x), 0.5f * (Zk.y - Zm.y));
            float2 O = make_float2(0.5f * (Zk.y + Zm.y), -0.5f * (Zk.x - Zm.x));
            float s, c;
            __sincosf((float)k * 3.0679615757712823e-3f, &s, &c);  // 2*pi/2048
            float2 X = make_float2(E.x + c * O.x + s * O.y,
                                   E.y + c * O.y - s * O.x);
            mag = sqrtf(X.x * X.x + X.y * X.y);
        }
        atomicAdd(amp + kk, mag * (1.0f / 256.0f));
    }
}

// ---------------------------------------------------------------------------
// Kernel 2 (fast path): tap-sum factorized 1D-stencil conv. CHUNK=1024 (halo
// factor 1.375) with dk staged in LDS as fp16 (25.4 KB) -> total 32.6 KB.
// Grid (512, 2): 1024 independent blocks. Meta inline; block (0,0) publishes
// meta to ws for the fallback kernel. Zeroes its slice of `out`.
// ---------------------------------------------------------------------------
__global__ __launch_bounds__(256) void conv_fast_kernel(
    const float* __restrict__ x,
    const float* __restrict__ w1, const float* __restrict__ b1,
    const float* __restrict__ w2, const float* __restrict__ b2,
    const float* __restrict__ amp,
    float* __restrict__ ws, float* __restrict__ out)
{
    __shared__ float xs[XSMAX];
    __shared__ _Float16 dk[9][HSTRIDE];

    const int tid = threadIdx.x;
    // zero out slice: 1024 blocks x 45 float4 = 46080 float4 = 184320 floats
    {
        const int bid = blockIdx.y * gridDim.x + blockIdx.x;
        if (tid < 45) {
            int idx = bid * 45 + tid;
            if (idx < (NB * HORIZON) / 4)
                ((float4*)out)[idx] = make_float4(0.f, 0.f, 0.f, 0.f);
        }
    }

    int P1, cols1, P2, cols2; float wg1, wg2;
    compute_meta(amp, xs, (int*)(xs + 512), tid, P1, cols1, P2, cols2, wg1, wg2);

    // publish meta for the fallback kernel (runs after this one completes)
    if (blockIdx.x == 0 && blockIdx.y == 0 && tid == 0) {
        int* mi = (int*)ws;
        mi[0] = P1; mi[1] = cols1; mi[2] = P2; mi[3] = cols2;
        ws[4] = wg1; ws[5] = wg2;
    }

    const int per  = blockIdx.y;
    const int P    = per == 0 ? P1 : P2;
    const int cols = per == 0 ? cols1 : cols2;
    if (P > PMAX_FAST) return;
    const float wgt = per == 0 ? wg1 : wg2;
    float* yout = ws + (per == 0 ? WS_Y0 : WS_Y1);

    const int b   = blockIdx.x >> 1;
    const int ci  = blockIdx.x & 1;
    const int t0  = ci * CHUNK;
    const int U0  = t0 - (P + 1);            // first h position
    const int HN  = CHUNK + 2 * P + 2;       // h positions incl. halo (<= 1408)
    const int X0  = t0 - (2 * P + 2);        // first x stage position
    const int XN  = CHUNK + 4 * P + 4;       // <= 1792

    __syncthreads();                         // meta scratch -> xs staging
    for (int j = tid; j < XN; j += 256) {
        int t = X0 + j;
        xs[j] = (t >= 0 && t < T_LEN) ? x[b * T_LEN + t] : 0.f;
    }
    __syncthreads();

    // phase 1: per position, 64 h's in registers, accumulate d[9] -> fp16 LDS
    for (int sidx = 0; sidx < 6; ++sidx) {
        const int i = tid + sidx * 256;
        if (i >= HN) break;
        const int u = U0 + i;
        const int uu = u < 0 ? 0 : u;
        const int cc = uu / P;
        const int pp = uu - cc * P;
        const bool rm = pp > 0, rp = pp < P - 1, cm = cc > 0, cp = (cc + 1) < cols;
        const int ibase = i + P + 1;          // xs index of tap center
        float xv[9];
        xv[0] = (rm && cm) ? xs[ibase - P - 1] : 0.f;
        xv[1] = rm         ? xs[ibase - 1]     : 0.f;
        xv[2] = (rm && cp) ? xs[ibase + P - 1] : 0.f;
        xv[3] = cm         ? xs[ibase - P]     : 0.f;
        xv[4] =              xs[ibase];
        xv[5] = cp         ? xs[ibase + P]     : 0.f;
        xv[6] = (rp && cm) ? xs[ibase - P + 1] : 0.f;
        xv[7] = rp         ? xs[ibase + 1]     : 0.f;
        xv[8] = (rp && cp) ? xs[ibase + P + 1] : 0.f;

        float d[9] = {0.f, 0.f, 0.f, 0.f, 0.f, 0.f, 0.f, 0.f, 0.f};
        #pragma unroll 4
        for (int ch = 0; ch < DMODEL; ++ch) {
            const float* wr1 = w1 + ch * 9;
            float a = b1[ch];
            #pragma unroll
            for (int k = 0; k < 9; ++k) a = fmaf(wr1[k], xv[k], a);
            float h = gelu_fast(a);
            const float* wr2 = w2 + ch * 9;
            #pragma unroll
            for (int k = 0; k < 9; ++k) d[k] = fmaf(wr2[k], h, d[k]);
        }
        #pragma unroll
        for (int k = 0; k < 9; ++k) dk[k][i] = (_Float16)d[k];
    }
    if (tid < 9) dk[tid][ZSLOT] = (_Float16)0.f;
    __syncthreads();

    // phase 2: gather 9 tap-sums per output (span exactly CHUNK=1024)
    const float bias2 = b2[0];
    #pragma unroll
    for (int o = 0; o < 4; ++o) {
        const int t = t0 + tid + o * 256;
        const int iout = tid + o * 256 + (P + 1);
        const int cc = t / P;
        const int pp = t - cc * P;
        const bool rm = pp > 0, rp = pp < P - 1, cm = cc > 0, cp = (cc + 1) < cols;
        const int i0 = (rm && cm) ? iout - P - 1 : ZSLOT;
        const int i1 = rm         ? iout - 1     : ZSLOT;
        const int i2 = (rm && cp) ? iout + P - 1 : ZSLOT;
        const int i3 = cm         ? iout - P     : ZSLOT;
        const int i5 = cp         ? iout + P     : ZSLOT;
        const int i6 = (rp && cm) ? iout - P + 1 : ZSLOT;
        const int i7 = rp         ? iout + 1     : ZSLOT;
        const int i8 = (rp && cp) ? iout + P + 1 : ZSLOT;
        float s = (float)dk[4][iout];
        s += (float)dk[0][i0]; s += (float)dk[1][i1]; s += (float)dk[2][i2];
        s += (float)dk[3][i3]; s += (float)dk[5][i5]; s += (float)dk[6][i6];
        s += (float)dk[7][i7]; s += (float)dk[8][i8];
        yout[b * T_LEN + t] = wgt * (s + bias2);
    }
}

// ---------------------------------------------------------------------------
// Kernel 2b (fallback, P > PMAX_FAST): 2D tile version, grid-stride.
// Reads precomputed meta from ws. Usually a noop dispatch.
// ---------------------------------------------------------------------------
__global__ __launch_bounds__(256) void conv_unit_kernel(
    const float* __restrict__ x,
    const float* __restrict__ w1, const float* __restrict__ b1,
    const float* __restrict__ w2, const float* __restrict__ b2,
    float* __restrict__ ws)
{
    const int* mi = (const int*)ws;
    const int per   = blockIdx.y;
    const int P     = mi[per * 2 + 0];
    const int cols  = mi[per * 2 + 1];
    if (P <= PMAX_FAST) return;
    const float wgt = ws[4 + per];
    float* yout = ws + (per == 0 ? WS_Y0 : WS_Y1);

    __shared__ float w1s[DMODEL * 9];
    __shared__ float w2s[DMODEL * 9];
    __shared__ float b1s[DMODEL];
    __shared__ float xs[12][13];
    __shared__ float hs[DMODEL][101];

    const int tid = threadIdx.x;
    for (int i = tid; i < DMODEL * 9; i += 256) { w1s[i] = w1[i]; w2s[i] = w2[i]; }
    if (tid < DMODEL) b1s[tid] = b1[tid];
    const float bias2 = b2[0];

    const int tp = (P + 7) >> 3;
    const int tc = (cols + 7) >> 3;
    const int tiles_img = tp * tc;
    const int total = tiles_img * NB;

    for (int tile = blockIdx.x; tile < total; tile += gridDim.x) {
        const int b   = tile / tiles_img;
        const int ti  = tile - b * tiles_img;
        const int tpi = ti / tc;
        const int tci = ti - tpi * tc;
        const int p0 = tpi * 8, c0 = tci * 8;

        __syncthreads();
        if (tid < 144) {
            int i = tid / 12, j = tid - (tid / 12) * 12;
            int pp = p0 - 2 + i, cc = c0 - 2 + j;
            float v = 0.f;
            if (pp >= 0 && pp < P && cc >= 0 && cc < cols) {
                int t = cc * P + pp;
                if (t < T_LEN) v = x[b * T_LEN + t];
            }
            xs[i][j] = v;
        }
        __syncthreads();

        #pragma unroll
        for (int it = 0; it < 25; ++it) {
            int idx = it * 256 + tid;
            int ch = idx / 100;
            int px = idx - ch * 100;
            int pi = px / 10;
            int pj = px - pi * 10;
            const float* w = &w1s[ch * 9];
            float a = b1s[ch];
            a = fmaf(w[0], xs[pi    ][pj    ], a);
            a = fmaf(w[1], xs[pi    ][pj + 1], a);
            a = fmaf(w[2], xs[pi    ][pj + 2], a);
            a = fmaf(w[3], xs[pi + 1][pj    ], a);
            a = fmaf(w[4], xs[pi + 1][pj + 1], a);
            a = fmaf(w[5], xs[pi + 1][pj + 2], a);
            a = fmaf(w[6], xs[pi + 2][pj    ], a);
            a = fmaf(w[7], xs[pi + 2][pj + 1], a);
            a = fmaf(w[8], xs[pi + 2][pj + 2], a);
            float g = gelu_fast(a);
            int pp = p0 - 1 + pi, cc = c0 - 1 + pj;
            bool in_img = (pp >= 0) & (pp < P) & (cc >= 0) & (cc < cols);
            hs[ch][px] = in_img ? g : 0.0f;
        }
        __syncthreads();

        {
            const int pixel = tid >> 2, part = tid & 3;
            const int pi = pixel >> 3, pj = pixel & 7;
            const int base = pi * 10 + pj;
            float s = 0.f;
            for (int ch = part * 16; ch < part * 16 + 16; ++ch) {
                const float* w  = &w2s[ch * 9];
                const float* hr = &hs[ch][base];
                s = fmaf(w[0], hr[0],  s);
                s = fmaf(w[1], hr[1],  s);
                s = fmaf(w[2], hr[2],  s);
                s = fmaf(w[3], hr[10], s);
                s = fmaf(w[4], hr[11], s);
                s = fmaf(w[5], hr[12], s);
                s = fmaf(w[6], hr[20], s);
                s = fmaf(w[7], hr[21], s);
                s = fmaf(w[8], hr[22], s);
            }
            s += __shfl_down(s, 1);
            s += __shfl_down(s, 2);
            if (part == 0) {
                int pp = p0 + pi, cc = c0 + pj;
                if (pp < P && cc < cols) {
                    int t = cc * P + pp;
                    if (t < T_LEN) yout[b * T_LEN + t] = wgt * (s + bias2);
                }
            }
        }
    }
}

// ---------------------------------------------------------------------------
// Kernel 3: split-K head GEMM, float4 staging. grid (8, 23, 4): 32x32 tile,
// K-chunk 512. Partials atomicAdd'ed into out (zeroed by conv_fast);
// z==0 adds bias.
// ---------------------------------------------------------------------------
__global__ __launch_bounds__(256) void head_gemm_kernel(
    const float* __restrict__ ws, const float* __restrict__ hw,
    const float* __restrict__ hb, float* __restrict__ out)
{
    const float* y0 = ws + WS_Y0;
    const float* y1 = ws + WS_Y1;
    const int b0 = blockIdx.x * 32, h0 = blockIdx.y * 32;
    const int kc0 = blockIdx.z * 512;
    __shared__ float As[32][33];
    __shared__ float Bs[32][33];
    const int tid = threadIdx.x;
    const int tx = tid & 15, ty = tid >> 4;
    const int i0 = ty * 2, j0 = tx * 2;
    const int sr = tid >> 3;             // staging row 0..31
    const int sc = (tid & 7) * 4;        // staging col 0,4,...,28
    float a00 = 0.f, a01 = 0.f, a10 = 0.f, a11 = 0.f;
    for (int k0 = kc0; k0 < kc0 + 512; k0 += 32) {
        {
            const int src = (b0 + sr) * T_LEN + k0 + sc;
            float4 u = *(const float4*)(y0 + src);
            float4 v = *(const float4*)(y1 + src);
            As[sr][sc]     = u.x + v.x;
            As[sr][sc + 1] = u.y + v.y;
            As[sr][sc + 2] = u.z + v.z;
            As[sr][sc + 3] = u.w + v.w;
            const int hrow = h0 + sr;
            float4 w = (hrow < HORIZON) ? *(const float4*)(hw + hrow * T_LEN + k0 + sc)
                                        : make_float4(0.f, 0.f, 0.f, 0.f);
            Bs[sr][sc]     = w.x;
            Bs[sr][sc + 1] = w.y;
            Bs[sr][sc + 2] = w.z;
            Bs[sr][sc + 3] = w.w;
        }
        __syncthreads();
        #pragma unroll
        for (int kk = 0; kk < 32; ++kk) {
            float av0 = As[i0][kk], av1 = As[i0 + 1][kk];
            float bv0 = Bs[j0][kk], bv1 = Bs[j0 + 1][kk];
            a00 = fmaf(av0, bv0, a00); a01 = fmaf(av0, bv1, a01);
            a10 = fmaf(av1, bv0, a10); a11 = fmaf(av1, bv1, a11);
        }
        __syncthreads();
    }
    const int bi = b0 + i0, hj = h0 + j0;
    if (blockIdx.z == 0) {
        if (hj < HORIZON)     { float bb = hb[hj];     a00 += bb; a10 += bb; }
        if (hj + 1 < HORIZON) { float bb = hb[hj + 1]; a01 += bb; a11 += bb; }
    }
    if (hj < HORIZON) {
        atomicAdd(&out[bi * HORIZON + hj], a00);
        atomicAdd(&out[(bi + 1) * HORIZON + hj], a10);
    }
    if (hj + 1 < HORIZON) {
        atomicAdd(&out[bi * HORIZON + hj + 1], a01);
        atomicAdd(&out[(bi + 1) * HORIZON + hj + 1], a11);
    }
}

// ---------------------------------------------------------------------------
extern "C" void kernel_launch(void* const* d_in, const int* in_sizes, int n_in,
                              void* d_out, int out_size, void* d_ws, size_t ws_size,
                              hipStream_t stream) {
    const float* x   = (const float*)d_in[0];
    const float* c1w = (const float*)d_in[1];
    const float* c1b = (const float*)d_in[2];
    const float* c2w = (const float*)d_in[3];
    const float* c2b = (const float*)d_in[4];
    const float* hw  = (const float*)d_in[5];
    const float* hb  = (const float*)d_in[6];
    float* out = (float*)d_out;
    float* ws  = (float*)d_ws;

    float* amp = ws + WS_AMP;

    hipMemsetAsync(amp, 0, N_FREQ * sizeof(float), stream);
    fft_amp_kernel<<<NB, 256, 0, stream>>>(x, amp);
    conv_fast_kernel<<<dim3(NB * NCHUNK, 2), 256, 0, stream>>>(x, c1w, c1b, c2w, c2b, amp, ws, out);
    conv_unit_kernel<<<dim3(256, 2), 256, 0, stream>>>(x, c1w, c1b, c2w, c2b, ws);
    head_gemm_kernel<<<dim3(NB / 32, (HORIZON + 31) / 32, 4), 256, 0, stream>>>(ws, hw, hb, out);
}

// Round 20
// 170.850 us; speedup vs baseline: 1.1257x; 1.0164x over previous
//
#include <hip/hip_runtime.h>
#include <math.h>

#define T_LEN   2048
#define NB      256
#define N_FREQ  1024
#define DMODEL  64
#define HORIZON 720

// ws layout in floats
#define WS_META 0                     // mi[0..3] ints, mf[4..5] floats (conv_fast -> conv_unit)
#define WS_AMP  64                    // 1024 floats, memset to 0 each launch
#define WS_Y0   2048
#define WS_Y1   (2048 + NB * T_LEN)

#define PMAX_FAST 191   // fast conv path handles P <= this; tile kernel covers rest
#define CHUNK   1024    // outputs per block in fast conv (4 per thread)
#define NCHUNK  2       // 2048/1024 exactly
#define HSTRIDE 1412    // fp16 dk stride: HN_max (1024+2*191+2 = 1408) + zslot
#define ZSLOT   1408
#define XSMAX   1792    // CHUNK + 4*191 + 4

// cheap tanh-GELU: a*rcp(1+exp(a*(c1+c2*a^2)))
__device__ __forceinline__ float gelu_fast(float a) {
    float a2 = a * a;
    float z  = a * fmaf(-0.07135481627159498f, a2, -1.5957691216057308f);
    float e  = __expf(z);
    return a * __builtin_amdgcn_rcpf(1.0f + e);
}

__device__ __forceinline__ float2 cmul(float2 a, float2 b) {
    return make_float2(a.x * b.x - a.y * b.y, a.x * b.y + a.y * b.x);
}

// ---------------------------------------------------------------------------
// Inline top-2 of amp (4 KB) + period/weight derivation, per block.
// ---------------------------------------------------------------------------
__device__ __forceinline__ void compute_meta(const float* __restrict__ amp,
                                             float* sf, int* si, int tid,
                                             int& P1, int& cols1, int& P2, int& cols2,
                                             float& wg1, float& wg2) {
    float* v1s = sf;        float* v2s = sf + 256;
    int*   i1s = si;        int*   i2s = si + 256;
    float4 v4 = ((const float4*)amp)[tid];
    float vv[4] = {v4.x, v4.y, v4.z, v4.w};
    float v1 = -1e30f, v2 = -1e30f; int i1 = 1 << 30, i2 = 1 << 30;
    #pragma unroll
    for (int u = 0; u < 4; ++u) {
        int j = tid * 4 + u;
        float v = vv[u];
        if (v > v1) { v2 = v1; i2 = i1; v1 = v; i1 = j; }
        else if (v > v2) { v2 = v; i2 = j; }
    }
    v1s[tid] = v1; i1s[tid] = i1; v2s[tid] = v2; i2s[tid] = i2;
    __syncthreads();
    for (int st = 128; st > 0; st >>= 1) {
        if (tid < st) {
            float w1 = v1s[tid + st]; int j1 = i1s[tid + st];
            float w2 = v2s[tid + st]; int j2 = i2s[tid + st];
            float a1 = v1s[tid];      int a1i = i1s[tid];
            float a2 = v2s[tid];      int a2i = i2s[tid];
            float n1, n2; int n1i, n2i;
            bool w1_first = (w1 > a1) || (w1 == a1 && j1 < a1i);
            if (w1_first) {
                n1 = w1; n1i = j1;
                bool a1_next = (a1 > w2) || (a1 == w2 && a1i < j2);
                if (a1_next) { n2 = a1; n2i = a1i; } else { n2 = w2; n2i = j2; }
            } else {
                n1 = a1; n1i = a1i;
                bool w1_next = (w1 > a2) || (w1 == a2 && j1 < a2i);
                if (w1_next) { n2 = w1; n2i = j1; } else { n2 = a2; n2i = a2i; }
            }
            v1s[tid] = n1; i1s[tid] = n1i; v2s[tid] = n2; i2s[tid] = n2i;
        }
        __syncthreads();
    }
    float v1f = v1s[0], v2f = v2s[0];
    int f1 = i1s[0] + 1, f2 = i2s[0] + 1;
    __syncthreads();                 // scratch free for reuse after this
    P1 = (int)llround(2048.0 / (double)f1); if (P1 < 1) P1 = 1;
    P2 = (int)llround(2048.0 / (double)f2); if (P2 < 1) P2 = 1;
    cols1 = (T_LEN + P1 - 1) / P1;
    cols2 = (T_LEN + P2 - 1) / P2;
    float mx = fmaxf(v1f, v2f);
    float e1 = __expf(v1f - mx), e2 = __expf(v2f - mx);
    float inv = 1.0f / (e1 + e2);
    wg1 = e1 * inv; wg2 = e2 * inv;
}

// ---------------------------------------------------------------------------
// Kernel 1: dual-batch packed 2048-pt FFT, radix-2^2 Stockham (5 fused double
// stages + 1 radix-2), 6 barriers. Unpack X_a/X_b, local-sum magnitudes,
// rotated atomicAdd into amp.
// ---------------------------------------------------------------------------
__global__ __launch_bounds__(1024) void fft_amp_kernel(const float* __restrict__ x,
                                                       float* __restrict__ amp) {
    __shared__ float2 buf0[2048];
    __shared__ float2 buf1[2048];
    __shared__ float2 tw[1024];
    const int tid = threadIdx.x;
    const int b = blockIdx.x;          // handles batches 2b, 2b+1

    {
        float s, c;
        __sincosf((float)tid * 3.0679615757712823e-3f, &s, &c);  // 2*pi/2048
        tw[tid] = make_float2(c, -s);
    }
    const float* xa = x + (2 * b) * T_LEN;
    const float* xb = x + (2 * b + 1) * T_LEN;
    buf0[tid]        = make_float2(xa[tid],        xb[tid]);
    buf0[tid + 1024] = make_float2(xa[tid + 1024], xb[tid + 1024]);
    __syncthreads();

    float2* src = buf0;
    float2* dst = buf1;
    // 5 fused double stages: s = 0,2,4,6,8
    for (int s = 0; s < 10; s += 2) {
        const int Ns = 1 << s;
        if (tid < 512) {
            const int j1 = tid;
            const int q  = j1 & (Ns - 1);
            const int hi = j1 >> s;
            float2 A = src[j1];
            float2 B = src[j1 + 1024];
            float2 C = src[j1 + 512];
            float2 D = src[j1 + 1536];
            float2 w  = tw[q << (10 - s)];
            float2 wB = cmul(w, B);
            float2 wD = cmul(w, D);
            float2 P0 = make_float2(A.x + wB.x, A.y + wB.y);
            float2 P1 = make_float2(A.x - wB.x, A.y - wB.y);
            float2 Q0 = make_float2(C.x + wD.x, C.y + wD.y);
            float2 Q1 = make_float2(C.x - wD.x, C.y - wD.y);
            float2 wa = tw[q << (9 - s)];
            float2 wb = tw[(q + Ns) << (9 - s)];
            float2 t0 = cmul(wa, Q0);
            float2 t1 = cmul(wb, Q1);
            const int O = (hi << (s + 2)) + q;
            dst[O]          = make_float2(P0.x + t0.x, P0.y + t0.y);
            dst[O + 2 * Ns] = make_float2(P0.x - t0.x, P0.y - t0.y);
            dst[O + Ns]     = make_float2(P1.x + t1.x, P1.y + t1.y);
            dst[O + 3 * Ns] = make_float2(P1.x - t1.x, P1.y - t1.y);
        }
        __syncthreads();
        float2* tmp = src; src = dst; dst = tmp;
    }
    // final radix-2 stage, s=10 (Ns=1024): base = q = tid
    {
        float2 a  = src[tid];
        float2 bb = src[tid + 1024];
        float2 w  = tw[tid];
        float2 t  = cmul(w, bb);
        dst[tid]        = make_float2(a.x + t.x, a.y + t.y);
        dst[tid + 1024] = make_float2(a.x - t.x, a.y - t.y);
        __syncthreads();
        float2* tmp = src; src = dst; dst = tmp;
    }
    // natural order in src; per-block rotated k to spread atomic contention
    const int kk = (tid + b * 8) & 1023;   // amp index, freq k = kk+1
    const int k = kk + 1;
    float2 Zk = src[k];
    float2 Zn = src[2048 - k];
    float ar = 0.5f * (Zk.x + Zn.x), ai = 0.5f * (Zk.y - Zn.y);
    float br = 0.5f * (Zk.y + Zn.y), bi = 0.5f * (Zk.x - Zn.x);
    float mag = (sqrtf(ar * ar + ai * ai) + sqrtf(br * br + bi * bi)) * (1.0f / 256.0f);
    atomicAdd(amp + kk, mag);
}

// ---------------------------------------------------------------------------
// Kernel 2 (fast path): tap-sum factorized 1D-stencil conv. CHUNK=1024 (halo
// factor 1.375) with dk staged in LDS as fp16 (25.4 KB) -> total 32.6 KB.
// Grid (512, 2): 1024 independent blocks. Meta inline; block (0,0) publishes
// meta to ws for the fallback kernel. Zeroes its slice of `out`.
// ---------------------------------------------------------------------------
__global__ __launch_bounds__(256) void conv_fast_kernel(
    const float* __restrict__ x,
    const float* __restrict__ w1, const float* __restrict__ b1,
    const float* __restrict__ w2, const float* __restrict__ b2,
    const float* __restrict__ amp,
    float* __restrict__ ws, float* __restrict__ out)
{
    __shared__ float xs[XSMAX];
    __shared__ _Float16 dk[9][HSTRIDE];

    const int tid = threadIdx.x;
    // zero out slice: 1024 blocks x 45 float4 = 46080 float4 = 184320 floats
    {
        const int bid = blockIdx.y * gridDim.x + blockIdx.x;
        if (tid < 45) {
            int idx = bid * 45 + tid;
            if (idx < (NB * HORIZON) / 4)
                ((float4*)out)[idx] = make_float4(0.f, 0.f, 0.f, 0.f);
        }
    }

    int P1, cols1, P2, cols2; float wg1, wg2;
    compute_meta(amp, xs, (int*)(xs + 512), tid, P1, cols1, P2, cols2, wg1, wg2);

    // publish meta for the fallback kernel (runs after this one completes)
    if (blockIdx.x == 0 && blockIdx.y == 0 && tid == 0) {
        int* mi = (int*)ws;
        mi[0] = P1; mi[1] = cols1; mi[2] = P2; mi[3] = cols2;
        ws[4] = wg1; ws[5] = wg2;
    }

    const int per  = blockIdx.y;
    const int P    = per == 0 ? P1 : P2;
    const int cols = per == 0 ? cols1 : cols2;
    if (P > PMAX_FAST) return;
    const float wgt = per == 0 ? wg1 : wg2;
    float* yout = ws + (per == 0 ? WS_Y0 : WS_Y1);

    const int b   = blockIdx.x >> 1;
    const int ci  = blockIdx.x & 1;
    const int t0  = ci * CHUNK;
    const int U0  = t0 - (P + 1);            // first h position
    const int HN  = CHUNK + 2 * P + 2;       // h positions incl. halo (<= 1408)
    const int X0  = t0 - (2 * P + 2);        // first x stage position
    const int XN  = CHUNK + 4 * P + 4;       // <= 1792

    __syncthreads();                         // meta scratch -> xs staging
    for (int j = tid; j < XN; j += 256) {
        int t = X0 + j;
        xs[j] = (t >= 0 && t < T_LEN) ? x[b * T_LEN + t] : 0.f;
    }
    __syncthreads();

    // phase 1: per position, 64 h's in registers, accumulate d[9] -> fp16 LDS
    for (int sidx = 0; sidx < 6; ++sidx) {
        const int i = tid + sidx * 256;
        if (i >= HN) break;
        const int u = U0 + i;
        const int uu = u < 0 ? 0 : u;
        const int cc = uu / P;
        const int pp = uu - cc * P;
        const bool rm = pp > 0, rp = pp < P - 1, cm = cc > 0, cp = (cc + 1) < cols;
        const int ibase = i + P + 1;          // xs index of tap center
        float xv[9];
        xv[0] = (rm && cm) ? xs[ibase - P - 1] : 0.f;
        xv[1] = rm         ? xs[ibase - 1]     : 0.f;
        xv[2] = (rm && cp) ? xs[ibase + P - 1] : 0.f;
        xv[3] = cm         ? xs[ibase - P]     : 0.f;
        xv[4] =              xs[ibase];
        xv[5] = cp         ? xs[ibase + P]     : 0.f;
        xv[6] = (rp && cm) ? xs[ibase - P + 1] : 0.f;
        xv[7] = rp         ? xs[ibase + 1]     : 0.f;
        xv[8] = (rp && cp) ? xs[ibase + P + 1] : 0.f;

        float d[9] = {0.f, 0.f, 0.f, 0.f, 0.f, 0.f, 0.f, 0.f, 0.f};
        #pragma unroll 4
        for (int ch = 0; ch < DMODEL; ++ch) {
            const float* wr1 = w1 + ch * 9;
            float a = b1[ch];
            #pragma unroll
            for (int k = 0; k < 9; ++k) a = fmaf(wr1[k], xv[k], a);
            float h = gelu_fast(a);
            const float* wr2 = w2 + ch * 9;
            #pragma unroll
            for (int k = 0; k < 9; ++k) d[k] = fmaf(wr2[k], h, d[k]);
        }
        #pragma unroll
        for (int k = 0; k < 9; ++k) dk[k][i] = (_Float16)d[k];
    }
    if (tid < 9) dk[tid][ZSLOT] = (_Float16)0.f;
    __syncthreads();

    // phase 2: gather 9 tap-sums per output (span exactly CHUNK=1024)
    const float bias2 = b2[0];
    #pragma unroll
    for (int o = 0; o < 4; ++o) {
        const int t = t0 + tid + o * 256;
        const int iout = tid + o * 256 + (P + 1);
        const int cc = t / P;
        const int pp = t - cc * P;
        const bool rm = pp > 0, rp = pp < P - 1, cm = cc > 0, cp = (cc + 1) < cols;
        const int i0 = (rm && cm) ? iout - P - 1 : ZSLOT;
        const int i1 = rm         ? iout - 1     : ZSLOT;
        const int i2 = (rm && cp) ? iout + P - 1 : ZSLOT;
        const int i3 = cm         ? iout - P     : ZSLOT;
        const int i5 = cp         ? iout + P     : ZSLOT;
        const int i6 = (rp && cm) ? iout - P + 1 : ZSLOT;
        const int i7 = rp         ? iout + 1     : ZSLOT;
        const int i8 = (rp && cp) ? iout + P + 1 : ZSLOT;
        float s = (float)dk[4][iout];
        s += (float)dk[0][i0]; s += (float)dk[1][i1]; s += (float)dk[2][i2];
        s += (float)dk[3][i3]; s += (float)dk[5][i5]; s += (float)dk[6][i6];
        s += (float)dk[7][i7]; s += (float)dk[8][i8];
        yout[b * T_LEN + t] = wgt * (s + bias2);
    }
}

// ---------------------------------------------------------------------------
// Kernel 2b (fallback, P > PMAX_FAST): 2D tile version, grid-stride.
// Reads precomputed meta from ws. Usually a noop dispatch.
// ---------------------------------------------------------------------------
__global__ __launch_bounds__(256) void conv_unit_kernel(
    const float* __restrict__ x,
    const float* __restrict__ w1, const float* __restrict__ b1,
    const float* __restrict__ w2, const float* __restrict__ b2,
    float* __restrict__ ws)
{
    const int* mi = (const int*)ws;
    const int per   = blockIdx.y;
    const int P     = mi[per * 2 + 0];
    const int cols  = mi[per * 2 + 1];
    if (P <= PMAX_FAST) return;
    const float wgt = ws[4 + per];
    float* yout = ws + (per == 0 ? WS_Y0 : WS_Y1);

    __shared__ float w1s[DMODEL * 9];
    __shared__ float w2s[DMODEL * 9];
    __shared__ float b1s[DMODEL];
    __shared__ float xs[12][13];
    __shared__ float hs[DMODEL][101];

    const int tid = threadIdx.x;
    for (int i = tid; i < DMODEL * 9; i += 256) { w1s[i] = w1[i]; w2s[i] = w2[i]; }
    if (tid < DMODEL) b1s[tid] = b1[tid];
    const float bias2 = b2[0];

    const int tp = (P + 7) >> 3;
    const int tc = (cols + 7) >> 3;
    const int tiles_img = tp * tc;
    const int total = tiles_img * NB;

    for (int tile = blockIdx.x; tile < total; tile += gridDim.x) {
        const int b   = tile / tiles_img;
        const int ti  = tile - b * tiles_img;
        const int tpi = ti / tc;
        const int tci = ti - tpi * tc;
        const int p0 = tpi * 8, c0 = tci * 8;

        __syncthreads();
        if (tid < 144) {
            int i = tid / 12, j = tid - (tid / 12) * 12;
            int pp = p0 - 2 + i, cc = c0 - 2 + j;
            float v = 0.f;
            if (pp >= 0 && pp < P && cc >= 0 && cc < cols) {
                int t = cc * P + pp;
                if (t < T_LEN) v = x[b * T_LEN + t];
            }
            xs[i][j] = v;
        }
        __syncthreads();

        #pragma unroll
        for (int it = 0; it < 25; ++it) {
            int idx = it * 256 + tid;
            int ch = idx / 100;
            int px = idx - ch * 100;
            int pi = px / 10;
            int pj = px - pi * 10;
            const float* w = &w1s[ch * 9];
            float a = b1s[ch];
            a = fmaf(w[0], xs[pi    ][pj    ], a);
            a = fmaf(w[1], xs[pi    ][pj + 1], a);
            a = fmaf(w[2], xs[pi    ][pj + 2], a);
            a = fmaf(w[3], xs[pi + 1][pj    ], a);
            a = fmaf(w[4], xs[pi + 1][pj + 1], a);
            a = fmaf(w[5], xs[pi + 1][pj + 2], a);
            a = fmaf(w[6], xs[pi + 2][pj    ], a);
            a = fmaf(w[7], xs[pi + 2][pj + 1], a);
            a = fmaf(w[8], xs[pi + 2][pj + 2], a);
            float g = gelu_fast(a);
            int pp = p0 - 1 + pi, cc = c0 - 1 + pj;
            bool in_img = (pp >= 0) & (pp < P) & (cc >= 0) & (cc < cols);
            hs[ch][px] = in_img ? g : 0.0f;
        }
        __syncthreads();

        {
            const int pixel = tid >> 2, part = tid & 3;
            const int pi = pixel >> 3, pj = pixel & 7;
            const int base = pi * 10 + pj;
            float s = 0.f;
            for (int ch = part * 16; ch < part * 16 + 16; ++ch) {
                const float* w  = &w2s[ch * 9];
                const float* hr = &hs[ch][base];
                s = fmaf(w[0], hr[0],  s);
                s = fmaf(w[1], hr[1],  s);
                s = fmaf(w[2], hr[2],  s);
                s = fmaf(w[3], hr[10], s);
                s = fmaf(w[4], hr[11], s);
                s = fmaf(w[5], hr[12], s);
                s = fmaf(w[6], hr[20], s);
                s = fmaf(w[7], hr[21], s);
                s = fmaf(w[8], hr[22], s);
            }
            s += __shfl_down(s, 1);
            s += __shfl_down(s, 2);
            if (part == 0) {
                int pp = p0 + pi, cc = c0 + pj;
                if (pp < P && cc < cols) {
                    int t = cc * P + pp;
                    if (t < T_LEN) yout[b * T_LEN + t] = wgt * (s + bias2);
                }
            }
        }
    }
}

// ---------------------------------------------------------------------------
// Kernel 3: split-K head GEMM, float4 staging. grid (8, 23, 4): 32x32 tile,
// K-chunk 512. Partials atomicAdd'ed into out (zeroed by conv_fast);
// z==0 adds bias.
// ---------------------------------------------------------------------------
__global__ __launch_bounds__(256) void head_gemm_kernel(
    const float* __restrict__ ws, const float* __restrict__ hw,
    const float* __restrict__ hb, float* __restrict__ out)
{
    const float* y0 = ws + WS_Y0;
    const float* y1 = ws + WS_Y1;
    const int b0 = blockIdx.x * 32, h0 = blockIdx.y * 32;
    const int kc0 = blockIdx.z * 512;
    __shared__ float As[32][33];
    __shared__ float Bs[32][33];
    const int tid = threadIdx.x;
    const int tx = tid & 15, ty = tid >> 4;
    const int i0 = ty * 2, j0 = tx * 2;
    const int sr = tid >> 3;             // staging row 0..31
    const int sc = (tid & 7) * 4;        // staging col 0,4,...,28
    float a00 = 0.f, a01 = 0.f, a10 = 0.f, a11 = 0.f;
    for (int k0 = kc0; k0 < kc0 + 512; k0 += 32) {
        {
            const int src = (b0 + sr) * T_LEN + k0 + sc;
            float4 u = *(const float4*)(y0 + src);
            float4 v = *(const float4*)(y1 + src);
            As[sr][sc]     = u.x + v.x;
            As[sr][sc + 1] = u.y + v.y;
            As[sr][sc + 2] = u.z + v.z;
            As[sr][sc + 3] = u.w + v.w;
            const int hrow = h0 + sr;
            float4 w = (hrow < HORIZON) ? *(const float4*)(hw + hrow * T_LEN + k0 + sc)
                                        : make_float4(0.f, 0.f, 0.f, 0.f);
            Bs[sr][sc]     = w.x;
            Bs[sr][sc + 1] = w.y;
            Bs[sr][sc + 2] = w.z;
            Bs[sr][sc + 3] = w.w;
        }
        __syncthreads();
        #pragma unroll
        for (int kk = 0; kk < 32; ++kk) {
            float av0 = As[i0][kk], av1 = As[i0 + 1][kk];
            float bv0 = Bs[j0][kk], bv1 = Bs[j0 + 1][kk];
            a00 = fmaf(av0, bv0, a00); a01 = fmaf(av0, bv1, a01);
            a10 = fmaf(av1, bv0, a10); a11 = fmaf(av1, bv1, a11);
        }
        __syncthreads();
    }
    const int bi = b0 + i0, hj = h0 + j0;
    if (blockIdx.z == 0) {
        if (hj < HORIZON)     { float bb = hb[hj];     a00 += bb; a10 += bb; }
        if (hj + 1 < HORIZON) { float bb = hb[hj + 1]; a01 += bb; a11 += bb; }
    }
    if (hj < HORIZON) {
        atomicAdd(&out[bi * HORIZON + hj], a00);
        atomicAdd(&out[(bi + 1) * HORIZON + hj], a10);
    }
    if (hj + 1 < HORIZON) {
        atomicAdd(&out[bi * HORIZON + hj + 1], a01);
        atomicAdd(&out[(bi + 1) * HORIZON + hj + 1], a11);
    }
}

// ---------------------------------------------------------------------------
extern "C" void kernel_launch(void* const* d_in, const int* in_sizes, int n_in,
                              void* d_out, int out_size, void* d_ws, size_t ws_size,
                              hipStream_t stream) {
    const float* x   = (const float*)d_in[0];
    const float* c1w = (const float*)d_in[1];
    const float* c1b = (const float*)d_in[2];
    const float* c2w = (const float*)d_in[3];
    const float* c2b = (const float*)d_in[4];
    const float* hw  = (const float*)d_in[5];
    const float* hb  = (const float*)d_in[6];
    float* out = (float*)d_out;
    float* ws  = (float*)d_ws;

    float* amp = ws + WS_AMP;

    hipMemsetAsync(amp, 0, N_FREQ * sizeof(float), stream);
    fft_amp_kernel<<<NB / 2, 1024, 0, stream>>>(x, amp);
    conv_fast_kernel<<<dim3(NB * NCHUNK, 2), 256, 0, stream>>>(x, c1w, c1b, c2w, c2b, amp, ws, out);
    conv_unit_kernel<<<dim3(256, 2), 256, 0, stream>>>(x, c1w, c1b, c2w, c2b, ws);
    head_gemm_kernel<<<dim3(NB / 32, (HORIZON + 31) / 32, 4), 256, 0, stream>>>(ws, hw, hb, out);
}